// Round 1
// baseline (787.894 us; speedup 1.0000x reference)
//
#include <hip/hip_runtime.h>

#define BB 128       // batch
#define DD 128       // feature dim
#define KK1 2048     // K+1
#define NROWS 200000 // memory bank rows

static constexpr float INV_T = 1.0f / 0.07f;
static constexpr float MOM = 0.5f;

// ---------------------------------------------------------------------------
// outs[6, B, K1]: six gathered dot products. One wave per (b,k) pair.
// Lane i holds float2 covering elements [2i, 2i+1] of each gathered row.
// ---------------------------------------------------------------------------
__global__ __launch_bounds__(256) void outs_kernel(
    const float* __restrict__ l, const float* __restrict__ ab,
    const float* __restrict__ ori, const float* __restrict__ comp,
    const int* __restrict__ idx,
    const float* __restrict__ ml, const float* __restrict__ mab,
    const float* __restrict__ mori, const float* __restrict__ mcomp,
    float* __restrict__ outs) {
  const int gid = blockIdx.x * blockDim.x + threadIdx.x;
  const int wave = gid >> 6;          // global wave id == b*K1 + k
  const int lane = threadIdx.x & 63;
  if (wave >= BB * KK1) return;
  const int b = wave >> 11;           // K1 = 2048

  const int row = idx[wave];
  const size_t roff = (size_t)row * DD;

  const float2 wl    = ((const float2*)(ml    + roff))[lane];
  const float2 wab   = ((const float2*)(mab   + roff))[lane];
  const float2 wori  = ((const float2*)(mori  + roff))[lane];
  const float2 wcomp = ((const float2*)(mcomp + roff))[lane];

  const size_t voff = (size_t)b * DD;
  const float2 vl    = ((const float2*)(l    + voff))[lane];
  const float2 vab   = ((const float2*)(ab   + voff))[lane];
  const float2 vori  = ((const float2*)(ori  + voff))[lane];
  const float2 vcomp = ((const float2*)(comp + voff))[lane];

  // stack order: [l_ori, ab_l, ori_ab, ab_comp, l_comp, comp_ori]
  float d0 = wori.x  * vl.x    + wori.y  * vl.y;    // dot(w_ori, l)
  float d1 = wl.x    * vab.x   + wl.y    * vab.y;   // dot(w_l, ab)
  float d2 = wab.x   * vori.x  + wab.y   * vori.y;  // dot(w_ab, ori)
  float d3 = wcomp.x * vab.x   + wcomp.y * vab.y;   // dot(w_comp, ab)
  float d4 = wcomp.x * vl.x    + wcomp.y * vl.y;    // dot(w_comp, l)
  float d5 = wori.x  * vcomp.x + wori.y  * vcomp.y; // dot(w_ori, comp)

#pragma unroll
  for (int off = 32; off > 0; off >>= 1) {
    d0 += __shfl_down(d0, off);
    d1 += __shfl_down(d1, off);
    d2 += __shfl_down(d2, off);
    d3 += __shfl_down(d3, off);
    d4 += __shfl_down(d4, off);
    d5 += __shfl_down(d5, off);
  }

  if (lane == 0) {
    const int BK = BB * KK1;
    outs[0 * BK + wave] = d0 * INV_T;
    outs[1 * BK + wave] = d1 * INV_T;
    outs[2 * BK + wave] = d2 * INV_T;
    outs[3 * BK + wave] = d3 * INV_T;
    outs[4 * BK + wave] = d4 * INV_T;
    outs[5 * BK + wave] = d5 * INV_T;
  }
}

// ---------------------------------------------------------------------------
// Full copy of the 4 memory banks into the output (float4 grid-stride).
// ---------------------------------------------------------------------------
__global__ __launch_bounds__(256) void copy_banks(
    const float4* __restrict__ s0, const float4* __restrict__ s1,
    const float4* __restrict__ s2, const float4* __restrict__ s3,
    float4* __restrict__ d0, float4* __restrict__ d1,
    float4* __restrict__ d2, float4* __restrict__ d3) {
  const int n = NROWS * DD / 4; // 6,400,000 float4 per bank
  const int stride = gridDim.x * blockDim.x;
  for (int i = blockIdx.x * blockDim.x + threadIdx.x; i < n; i += stride) {
    d0[i] = s0[i];
    d1[i] = s1[i];
    d2[i] = s2[i];
    d3[i] = s3[i];
  }
}

// ---------------------------------------------------------------------------
// EMA update + L2 normalize for rows y. grid = (B, 4 banks), 64 threads.
// Last-write-wins on duplicate y (match numpy fancy-index set semantics).
// ---------------------------------------------------------------------------
__global__ __launch_bounds__(64) void ema_kernel(
    const float* __restrict__ l, const float* __restrict__ ab,
    const float* __restrict__ ori, const float* __restrict__ comp,
    const int* __restrict__ y,
    const float* __restrict__ ml, const float* __restrict__ mab,
    const float* __restrict__ mori, const float* __restrict__ mcomp,
    float* __restrict__ ol, float* __restrict__ oab,
    float* __restrict__ oori, float* __restrict__ ocomp) {
  const int b = blockIdx.x;
  const int bank = blockIdx.y;
  const int row = y[b];
  // last-write-wins: if a later b' targets the same row, this block bows out
  for (int b2 = b + 1; b2 < BB; ++b2)
    if (y[b2] == row) return;

  const float* v;
  const float* mem;
  float* out;
  switch (bank) {
    case 0: v = l;    mem = ml;    out = ol;    break;
    case 1: v = ab;   mem = mab;   out = oab;   break;
    case 2: v = ori;  mem = mori;  out = oori;  break;
    default: v = comp; mem = mcomp; out = ocomp; break;
  }

  const int lane = threadIdx.x;
  const float2 m2 = ((const float2*)(mem + (size_t)row * DD))[lane];
  const float2 v2 = ((const float2*)(v + (size_t)b * DD))[lane];
  float2 p;
  p.x = m2.x * MOM + v2.x * (1.0f - MOM);
  p.y = m2.y * MOM + v2.y * (1.0f - MOM);

  float ss = p.x * p.x + p.y * p.y;
#pragma unroll
  for (int off = 32; off > 0; off >>= 1) ss += __shfl_down(ss, off);
  ss = __shfl(ss, 0);
  const float inv = 1.0f / sqrtf(ss);

  ((float2*)(out + (size_t)row * DD))[lane] = make_float2(p.x * inv, p.y * inv);
}

extern "C" void kernel_launch(void* const* d_in, const int* in_sizes, int n_in,
                              void* d_out, int out_size, void* d_ws, size_t ws_size,
                              hipStream_t stream) {
  const float* l     = (const float*)d_in[0];
  const float* ab    = (const float*)d_in[1];
  const float* ori   = (const float*)d_in[2];
  const float* comp  = (const float*)d_in[3];
  const int*   y     = (const int*)d_in[4];
  const int*   idx   = (const int*)d_in[5];
  const float* ml    = (const float*)d_in[6];
  const float* mab   = (const float*)d_in[7];
  const float* mori  = (const float*)d_in[8];
  const float* mcomp = (const float*)d_in[9];

  float* out = (float*)d_out;
  const size_t OUTS = (size_t)6 * BB * KK1;          // 1,572,864
  const size_t BANK = (size_t)NROWS * DD;            // 25,600,000
  float* o_outs  = out;
  float* o_ml    = out + OUTS;
  float* o_mab   = o_ml + BANK;
  float* o_mori  = o_mab + BANK;
  float* o_mcomp = o_mori + BANK;

  // 1) outs: 262,144 waves, 4 waves per 256-thread block
  {
    const int waves = BB * KK1;
    const int blocks = waves / 4; // 65,536
    outs_kernel<<<blocks, 256, 0, stream>>>(l, ab, ori, comp, idx,
                                            ml, mab, mori, mcomp, o_outs);
  }

  // 2) bank copies
  {
    copy_banks<<<4096, 256, 0, stream>>>(
        (const float4*)ml, (const float4*)mab, (const float4*)mori,
        (const float4*)mcomp, (float4*)o_ml, (float4*)o_mab,
        (float4*)o_mori, (float4*)o_mcomp);
  }

  // 3) EMA rows (after copy; stream-ordered)
  {
    dim3 grid(BB, 4);
    ema_kernel<<<grid, 64, 0, stream>>>(l, ab, ori, comp, y,
                                        ml, mab, mori, mcomp,
                                        o_ml, o_mab, o_mori, o_mcomp);
  }
}